// Round 3
// baseline (387.406 us; speedup 1.0000x reference)
//
#include <hip/hip_runtime.h>

// ProtoSAE fused: h = relu(BN(x@W1^T + b1)); enc = h@W2^T + b2; act = f(||enc-proto||^2)
// T=8192, NI=1024, L=128, H=128, P=64. bf16 MFMA.
// R3: counted-vmcnt phase schedule (T3+T4+T5). BM=256 tokens x BN=256 (2 latents),
//     8 waves, BK=32, 4-slot LDS ring (128 KB), tile staged 3 K-tiles ahead,
//     raw s_barrier + s_waitcnt vmcnt(8) at K-tile boundaries only.

#define NTOK 8192
#define NI   1024
#define NL   128
#define NH   128
#define NP   64

typedef __bf16 bf16x8 __attribute__((ext_vector_type(8)));
typedef float f32x4 __attribute__((ext_vector_type(4)));

static __device__ __forceinline__ unsigned short f2bf(float f) {
  union { float f; unsigned int u; } v; v.f = f;
  const unsigned int u = v.u;
  return (unsigned short)((u + 0x7fffu + ((u >> 16) & 1u)) >> 16);  // RNE
}

__global__ void cvt_f32_bf16(const float* __restrict__ in,
                             unsigned short* __restrict__ out, int n8) {
  const int i = blockIdx.x * blockDim.x + threadIdx.x;
  if (i >= n8) return;
  const float4* p = (const float4*)in;
  const float4 a = p[2 * i], b = p[2 * i + 1];
  unsigned short v[8] __attribute__((aligned(16))) = {
      f2bf(a.x), f2bf(a.y), f2bf(a.z), f2bf(a.w),
      f2bf(b.x), f2bf(b.y), f2bf(b.z), f2bf(b.w)};
  ((uint4*)out)[i] = *(const uint4*)v;
}

static __device__ __forceinline__ void async16(const void* g, void* l) {
  __builtin_amdgcn_global_load_lds(
      (const __attribute__((address_space(1))) unsigned int*)g,
      (__attribute__((address_space(3))) unsigned int*)l, 16, 0, 0);
}

// Block: 256 tokens x 2 latents, 512 threads (8 waves: wr=wave>>2 in {0,1} token half,
// wc=wave&3 col quarter). LDS: A ring slots [0,64K) 4x(256x32 bf16), B ring [64K,128K).
// Epilogue reuse: h [0,64K), W2 pair [64K,96K).
__global__ __launch_bounds__(512, 1) void proto_fused(
    const unsigned short* __restrict__ xb,    // [8192][1024] bf16
    const unsigned short* __restrict__ w1b,   // [16384][1024] bf16
    const unsigned short* __restrict__ w2b,   // [128][64][128] bf16
    const float* __restrict__ b1,
    const float* __restrict__ gamma, const float* __restrict__ beta,
    const float* __restrict__ rmean, const float* __restrict__ rvar,
    const float* __restrict__ b2,
    const float* __restrict__ protos,
    float* __restrict__ out)                  // [8192][128]
{
  __shared__ __attribute__((aligned(128))) char smem[131072];
  const int tid  = threadIdx.x;
  const int wave = tid >> 6;
  const int lane = tid & 63;
  const int l15  = lane & 15;
  const int l4   = lane >> 4;
  const int wr   = wave >> 2;
  const int wc   = wave & 3;
  const int t0   = blockIdx.x * 256;
  const int lp   = blockIdx.y;               // latent pair index (0..63)

  // staging source map: linear LDS chunk p = j*512+tid -> (row r = p>>2, phys chunk p&3)
  // logical chunk = phys ^ (r&3) ^ ((r>>2)&3)  (involution; read side uses same XOR)
  int sr[2], scl[2];
#pragma unroll
  for (int j = 0; j < 2; ++j) {
    const int p = j * 512 + tid;
    const int r = p >> 2;
    sr[j]  = r;
    scl[j] = (p & 3) ^ (r & 3) ^ ((r >> 2) & 3);
  }
  const unsigned short* srcA0 = xb  + (size_t)(t0 + sr[0]) * NI + scl[0] * 8;
  const unsigned short* srcA1 = xb  + (size_t)(t0 + sr[1]) * NI + scl[1] * 8;
  const unsigned short* srcB0 = w1b + (size_t)(lp * 256 + sr[0]) * NI + scl[0] * 8;
  const unsigned short* srcB1 = w1b + (size_t)(lp * 256 + sr[1]) * NI + scl[1] * 8;
  const int dst0 = tid * 16;

  // fragment read byte offsets within a slot (logical k-chunk = l4)
  int offA[8], offB[4];
#pragma unroll
  for (int m = 0; m < 8; ++m) {
    const int r = wr * 128 + m * 16 + l15;
    offA[m] = r * 64 + ((l4 ^ (r & 3) ^ ((r >> 2) & 3)) << 4);
  }
#pragma unroll
  for (int n = 0; n < 4; ++n) {
    const int r = wc * 64 + n * 16 + l15;
    offB[n] = r * 64 + ((l4 ^ (r & 3) ^ ((r >> 2) & 3)) << 4);
  }

  f32x4 acc[8][4] = {};

  auto stageA = [&](int t) {
    const int s = (t & 3) * 16384;
    async16(srcA0 + t * 32, smem + s + dst0);
    async16(srcA1 + t * 32, smem + s + 8192 + dst0);
  };
  auto stageB = [&](int t) {
    const int s = 65536 + (t & 3) * 16384;
    async16(srcB0 + t * 32, smem + s + dst0);
    async16(srcB1 + t * 32, smem + s + 8192 + dst0);
  };

  // prologue: tiles 0,1,2 in flight (12 loads); need tile 0 -> vmcnt(8)
  stageA(0); stageB(0); stageA(1); stageB(1); stageA(2); stageB(2);
  asm volatile("s_waitcnt vmcnt(8)" ::: "memory");
  asm volatile("s_barrier" ::: "memory");

  for (int t = 0; t < 32; ++t) {
    const int sA = (t & 3) * 16384;
    const int sB = 65536 + sA;
    const int tp = (t + 3 < 32) ? t + 3 : 31;   // dummy re-stage keeps vmcnt count uniform
    bf16x8 afr[4], bfr[4];
    // ---- phase 0: m-frags 0..3, read B once per K-tile ----
#pragma unroll
    for (int m = 0; m < 4; ++m) afr[m] = *(const bf16x8*)(smem + sA + offA[m]);
#pragma unroll
    for (int n = 0; n < 4; ++n) bfr[n] = *(const bf16x8*)(smem + sB + offB[n]);
    stageA(tp);
    asm volatile("s_barrier" ::: "memory");
    asm volatile("s_waitcnt lgkmcnt(0)" ::: "memory");
    __builtin_amdgcn_s_setprio(1);
#pragma unroll
    for (int m = 0; m < 4; ++m)
#pragma unroll
      for (int n = 0; n < 4; ++n)
        acc[m][n] = __builtin_amdgcn_mfma_f32_16x16x32_bf16(afr[m], bfr[n], acc[m][n], 0, 0, 0);
    __builtin_amdgcn_s_setprio(0);
    asm volatile("s_barrier" ::: "memory");
    // ---- phase 1: m-frags 4..7 (reuse bfr) ----
#pragma unroll
    for (int m = 0; m < 4; ++m) afr[m] = *(const bf16x8*)(smem + sA + offA[4 + m]);
    stageB(tp);
    asm volatile("s_barrier" ::: "memory");
    asm volatile("s_waitcnt lgkmcnt(0)" ::: "memory");
    __builtin_amdgcn_s_setprio(1);
#pragma unroll
    for (int m = 0; m < 4; ++m)
#pragma unroll
      for (int n = 0; n < 4; ++n)
        acc[4 + m][n] = __builtin_amdgcn_mfma_f32_16x16x32_bf16(afr[m], bfr[n], acc[4 + m][n], 0, 0, 0);
    __builtin_amdgcn_s_setprio(0);
    // K-tile boundary: tiles t+2, t+3 (8 loads) may stay in flight; tile t+1 must land
    asm volatile("s_waitcnt vmcnt(8)" ::: "memory");
    asm volatile("s_barrier" ::: "memory");
  }

  // ================= epilogue =================
  __syncthreads();
  // stage W2 latent pair: 128 rows x 128 h, [64K,96K), chunk ^= row&15
#pragma unroll
  for (int j = 0; j < 4; ++j) {
    const int q = j * 512 + tid;
    const int r = q >> 4;
    const int cl = (q & 15) ^ (r & 15);
    async16(w2b + (size_t)lp * 16384 + r * 128 + cl * 8, smem + 65536 + q * 16);
  }

  const int my_ep = wc >> 1;          // which latent this wave's acc columns belong to
  const int c0    = (wc & 1) * 64;

  for (int ep = 0; ep < 2; ++ep) {
    if (my_ep == ep) {
      // bias + BN + ReLU -> h bf16 [256][128] at [0,64K), chunk ^= row&15
#pragma unroll
      for (int n = 0; n < 4; ++n) {
        const int col = c0 + n * 16 + l15;
        const int gi  = (lp * 2 + ep) * NH + col;
        const float sc_ = gamma[gi] * rsqrtf(rvar[gi] + 1e-5f);
        const float bi  = beta[gi] - rmean[gi] * sc_;
        const float bb  = b1[gi];
        const int cchunk = col >> 3, cin = (col & 7) * 2;
#pragma unroll
        for (int m = 0; m < 8; ++m)
#pragma unroll
          for (int rr = 0; rr < 4; ++rr) {
            float v = (acc[m][n][rr] + bb) * sc_ + bi;
            v = v > 0.f ? v : 0.f;
            const int row = wr * 128 + m * 16 + l4 * 4 + rr;
            *(unsigned short*)(smem + row * 256 + ((cchunk ^ (row & 15)) << 4) + cin) = f2bf(v);
          }
      }
    }
    __syncthreads();   // drains vmcnt (W2) + lgkm (h writes)

    // GEMM2: enc = h @ W2_lat^T  (M=256, N=64, K=128); wave owns 32 token rows
    f32x4 acc2[2][4] = {};
#pragma unroll
    for (int kk = 0; kk < 4; ++kk) {
      bf16x8 a2[2], bw[4];
#pragma unroll
      for (int m2 = 0; m2 < 2; ++m2) {
        const int row = wave * 32 + m2 * 16 + l15;
        a2[m2] = *(const bf16x8*)(smem + row * 256 + (((kk * 4 + l4) ^ (row & 15)) << 4));
      }
#pragma unroll
      for (int n = 0; n < 4; ++n) {
        const int rp = n * 16 + l15;
        bw[n] = *(const bf16x8*)(smem + 65536 + ep * 16384 + rp * 256 +
                                 (((kk * 4 + l4) ^ (rp & 15)) << 4));
      }
#pragma unroll
      for (int m2 = 0; m2 < 2; ++m2)
#pragma unroll
        for (int n = 0; n < 4; ++n)
          acc2[m2][n] = __builtin_amdgcn_mfma_f32_16x16x32_bf16(a2[m2], bw[n], acc2[m2][n], 0, 0, 0);
    }

    // L2 distance + log activation
    const int lg = lp * 2 + ep;
    float pb[4], pp[4];
#pragma unroll
    for (int n = 0; n < 4; ++n) {
      pb[n] = b2[lg * NP + n * 16 + l15];
      pp[n] = protos[lg * NP + n * 16 + l15];
    }
    const float act_scale = 300.0f / logf(10000.0f);
#pragma unroll
    for (int m2 = 0; m2 < 2; ++m2)
#pragma unroll
      for (int rr = 0; rr < 4; ++rr) {
        float s = 0.f;
#pragma unroll
        for (int n = 0; n < 4; ++n) {
          const float e = acc2[m2][n][rr] + pb[n] - pp[n];
          s += e * e;
        }
        s += __shfl_xor(s, 1);
        s += __shfl_xor(s, 2);
        s += __shfl_xor(s, 4);
        s += __shfl_xor(s, 8);
        if (l15 == 0) {
          const float a = logf((s + 1.0f) / (s + 1e-4f)) * act_scale - 100.0f;
          out[(size_t)(t0 + wave * 32 + m2 * 16 + l4 * 4 + rr) * NL + lg] = a;
        }
      }
    __syncthreads();   // GEMM2 reads done before ep=1 overwrites h
  }
}

extern "C" void kernel_launch(void* const* d_in, const int* in_sizes, int n_in,
                              void* d_out, int out_size, void* d_ws, size_t ws_size,
                              hipStream_t stream) {
  const float* x      = (const float*)d_in[0];
  const float* W1     = (const float*)d_in[1];
  const float* b1     = (const float*)d_in[2];
  const float* gamma  = (const float*)d_in[3];
  const float* beta   = (const float*)d_in[4];
  const float* rmean  = (const float*)d_in[5];
  const float* rvar   = (const float*)d_in[6];
  const float* W2     = (const float*)d_in[7];
  const float* b2     = (const float*)d_in[8];
  const float* protos = (const float*)d_in[9];
  float* out = (float*)d_out;

  unsigned short* xb  = (unsigned short*)d_ws;
  unsigned short* w1b = xb + (size_t)NTOK * NI;
  unsigned short* w2b = w1b + (size_t)NL * NH * NI;

  {
    const int n8x = NTOK * NI / 8;
    cvt_f32_bf16<<<(n8x + 255) / 256, 256, 0, stream>>>(x, xb, n8x);
    const int n8w1 = NL * NH * NI / 8;
    cvt_f32_bf16<<<(n8w1 + 255) / 256, 256, 0, stream>>>(W1, w1b, n8w1);
    const int n8w2 = NL * NP * NH / 8;
    cvt_f32_bf16<<<(n8w2 + 255) / 256, 256, 0, stream>>>(W2, w2b, n8w2);
  }

  dim3 grid(NTOK / 256, NL / 2);
  proto_fused<<<grid, 512, 0, stream>>>(xb, w1b, w2b, b1, gamma, beta,
                                        rmean, rvar, b2, protos, out);
}

// Round 4
// 229.246 us; speedup vs baseline: 1.6899x; 1.6899x over previous
//
#include <hip/hip_runtime.h>

// ProtoSAE fused: h = relu(BN(x@W1^T + b1)); enc = h@W2^T + b2; act = f(||enc-proto||^2)
// T=8192, NI=1024, L=128, H=128, P=64.
// R4: GEMM1 in int8 (per-row symmetric quant, exact i32 accum, fp32 scale factorization)
//     on R2's proven 128x128-tile / 0-conflict-swizzle / 3-blocks-per-CU structure.
//     GEMM2 + epilogue unchanged (bf16).

#define NTOK 8192
#define NI   1024
#define NL   128
#define NH   128
#define NP   64

typedef __bf16 bf16x8 __attribute__((ext_vector_type(8)));
typedef float f32x4 __attribute__((ext_vector_type(4)));
typedef int   i32x4 __attribute__((ext_vector_type(4)));

static __device__ __forceinline__ unsigned short f2bf(float f) {
  union { float f; unsigned int u; } v; v.f = f;
  const unsigned int u = v.u;
  return (unsigned short)((u + 0x7fffu + ((u >> 16) & 1u)) >> 16);  // RNE
}

// W2 -> bf16 (8 elems/thread)
__global__ void cvt_f32_bf16(const float* __restrict__ in,
                             unsigned short* __restrict__ out, int n8) {
  const int i = blockIdx.x * blockDim.x + threadIdx.x;
  if (i >= n8) return;
  const float4* p = (const float4*)in;
  const float4 a = p[2 * i], b = p[2 * i + 1];
  unsigned short v[8] __attribute__((aligned(16))) = {
      f2bf(a.x), f2bf(a.y), f2bf(a.z), f2bf(a.w),
      f2bf(b.x), f2bf(b.y), f2bf(b.z), f2bf(b.w)};
  ((uint4*)out)[i] = *(const uint4*)v;
}

// per-row symmetric int8 quantization of a [nrows][1024] f32 matrix; 1 wave per row
__global__ void quant_rows_i8(const float* __restrict__ in,
                              signed char* __restrict__ outq,
                              float* __restrict__ scale, int nrows) {
  const int row = blockIdx.x * 4 + (threadIdx.x >> 6);
  if (row >= nrows) return;
  const int lane = threadIdx.x & 63;
  const float4* src = (const float4*)(in + (size_t)row * 1024);
  float4 v[4];
  float m = 0.f;
#pragma unroll
  for (int j = 0; j < 4; ++j) {
    v[j] = src[lane + 64 * j];
    m = fmaxf(m, fmaxf(fmaxf(fabsf(v[j].x), fabsf(v[j].y)),
                       fmaxf(fabsf(v[j].z), fabsf(v[j].w))));
  }
#pragma unroll
  for (int s = 1; s < 64; s <<= 1) m = fmaxf(m, __shfl_xor(m, s));
  m = fmaxf(m, 1e-20f);
  const float inv = 127.0f / m;
  if (lane == 0) scale[row] = m * (1.0f / 127.0f);
  unsigned int* dst = (unsigned int*)(outq + (size_t)row * 1024);
#pragma unroll
  for (int j = 0; j < 4; ++j) {
    const float qa = fminf(127.f, fmaxf(-127.f, v[j].x * inv));
    const float qb = fminf(127.f, fmaxf(-127.f, v[j].y * inv));
    const float qc = fminf(127.f, fmaxf(-127.f, v[j].z * inv));
    const float qd = fminf(127.f, fmaxf(-127.f, v[j].w * inv));
    const int a = (int)rintf(qa), b = (int)rintf(qb),
              c = (int)rintf(qc), d = (int)rintf(qd);
    dst[lane + 64 * j] = (unsigned)(a & 255) | ((unsigned)(b & 255) << 8) |
                         ((unsigned)(c & 255) << 16) | ((unsigned)(d & 255) << 24);
  }
}

static __device__ __forceinline__ void async16(const void* g, void* l) {
  __builtin_amdgcn_global_load_lds(
      (const __attribute__((address_space(1))) unsigned int*)g,
      (__attribute__((address_space(3))) unsigned int*)l, 16, 0, 0);
}

// Block: 128 tokens x 1 latent, 4 waves as 2x2 (token-half x hcol-half).
// LDS: A [0,16K) 128x128 i8 swz(r&7); B [16K,32K) same; W2s [32K,48K) 64x128 bf16
//      swz(r&15) persistent; epilogue hs [0,32K) 128x128 bf16 swz(r&15).
__global__ __launch_bounds__(256, 3) void proto_fused(
    const signed char* __restrict__ xq,       // [8192][1024] i8
    const signed char* __restrict__ w1q,      // [16384][1024] i8
    const unsigned short* __restrict__ w2b,   // [128][64][128] bf16
    const float* __restrict__ sx,             // [8192]
    const float* __restrict__ sw,             // [16384]
    const float* __restrict__ b1,
    const float* __restrict__ gamma, const float* __restrict__ beta,
    const float* __restrict__ rmean, const float* __restrict__ rvar,
    const float* __restrict__ b2,
    const float* __restrict__ protos,
    float* __restrict__ out)                  // [8192][128]
{
  __shared__ __attribute__((aligned(128))) char smem[49152];
  const int tid  = threadIdx.x;
  const int wave = tid >> 6;
  const int lane = tid & 63;
  const int l15  = lane & 15;
  const int l4   = lane >> 4;
  const int wr   = wave >> 1;
  const int wc   = wave & 1;
  const int t0   = blockIdx.x * 128;
  const int lat  = blockIdx.y;

  const int srow  = lane >> 3;                    // row within 8-row staging chunk
  const int scolb = ((lane & 7) ^ srow) * 16;     // swizzled source byte offset:
                                                  // phys chunk lane&7 <- logical ^ (row&7)

  i32x4 acc[4][4] = {};

  // ---- stage W2[lat] once: 64x128 bf16 -> smem+32768, chunk ^= row&15 swizzle ----
#pragma unroll
  for (int i = 0; i < 4; ++i) {
    const int r = wave * 4 + i * 16 + (lane >> 4);     // 0..63
    const int c = (lane & 15) ^ (r & 15);
    async16(w2b + (size_t)lat * NP * NH + r * NH + c * 8,
            smem + 32768 + (wave * 64 + i * 256) * 16);
  }

  auto stage = [&](int ks) {
    const int k0 = ks * 128;                       // i8 elems == bytes
#pragma unroll
    for (int j = 0; j < 4; ++j) {
      const int row = wave * 32 + j * 8 + srow;
      async16(xq + (size_t)(t0 + row) * NI + k0 + scolb,
              smem + (wave * 4 + j) * 1024);
      async16(w1q + (size_t)(lat * NH + row) * NI + k0 + scolb,
              smem + 16384 + (wave * 4 + j) * 1024);
    }
  };

  // ---- GEMM1 main loop: i8, BK=128, 8 K-steps, single-buffered (m97 structure) ----
  stage(0);
  const int rx = l15 & 7;
  for (int ks = 0; ks < 8; ++ks) {
    __syncthreads();
#pragma unroll
    for (int kk = 0; kk < 2; ++kk) {
      i32x4 a[4], b[4];
#pragma unroll
      for (int m = 0; m < 4; ++m)
        a[m] = *(const i32x4*)(smem + (wr * 64 + m * 16 + l15) * 128 +
                               (((kk * 4 + l4) ^ rx) << 4));
#pragma unroll
      for (int n = 0; n < 4; ++n)
        b[n] = *(const i32x4*)(smem + 16384 + (wc * 64 + n * 16 + l15) * 128 +
                               (((kk * 4 + l4) ^ rx) << 4));
#pragma unroll
      for (int m = 0; m < 4; ++m)
#pragma unroll
        for (int n = 0; n < 4; ++n)
          acc[m][n] = __builtin_amdgcn_mfma_i32_16x16x64_i8(a[m], b[n], acc[m][n], 0, 0, 0);
    }
    __syncthreads();
    if (ks + 1 < 8) stage(ks + 1);
  }

  // ---- epilogue 1: dequant + bias + BN(eval) + ReLU -> hs bf16 [128][128] swz(r&15) ----
  float sxv[4][4];
#pragma unroll
  for (int m = 0; m < 4; ++m)
#pragma unroll
    for (int r = 0; r < 4; ++r)
      sxv[m][r] = sx[t0 + wr * 64 + m * 16 + l4 * 4 + r];

#pragma unroll
  for (int n = 0; n < 4; ++n) {
    const int hc = wc * 64 + n * 16 + l15;
    const int gi = lat * NH + hc;
    const float swc = sw[gi];
    const float sc  = gamma[gi] * rsqrtf(rvar[gi] + 1e-5f);
    const float bi  = beta[gi] - rmean[gi] * sc;
    const float bb  = b1[gi];
#pragma unroll
    for (int m = 0; m < 4; ++m)
#pragma unroll
      for (int r = 0; r < 4; ++r) {
        const float hv = (float)acc[m][n][r] * sxv[m][r] * swc;
        float v = (hv + bb) * sc + bi;
        v = v > 0.f ? v : 0.f;
        const int row = wr * 64 + m * 16 + l4 * 4 + r;
        const int pbyte = row * 256 + (((hc >> 3) ^ (row & 15)) << 4) + (hc & 7) * 2;
        *(unsigned short*)(smem + pbyte) = f2bf(v);
      }
  }
  __syncthreads();

  // ---- epilogue 2: enc = h @ W2^T (M=128, N=64, K=128), bf16, swizzled reads ----
  f32x4 acc2[2][4] = {};
#pragma unroll
  for (int kk = 0; kk < 4; ++kk) {
    const int pcsel = kk * 4 + l4;
    bf16x8 a2[2], bw[4];
#pragma unroll
    for (int m = 0; m < 2; ++m) {
      const int row = wave * 32 + m * 16 + l15;
      a2[m] = *(const bf16x8*)(smem + row * 256 + ((pcsel ^ (row & 15)) << 4));
    }
#pragma unroll
    for (int n = 0; n < 4; ++n) {
      const int rp = n * 16 + l15;
      bw[n] = *(const bf16x8*)(smem + 32768 + rp * 256 + ((pcsel ^ (rp & 15)) << 4));
    }
#pragma unroll
    for (int m = 0; m < 2; ++m)
#pragma unroll
      for (int n = 0; n < 4; ++n)
        acc2[m][n] = __builtin_amdgcn_mfma_f32_16x16x32_bf16(a2[m], bw[n], acc2[m][n], 0, 0, 0);
  }

  // ---- epilogue 3: L2 distance to prototypes + log activation ----
  float pb[4], pp[4];
#pragma unroll
  for (int n = 0; n < 4; ++n) {
    const int p = n * 16 + l15;
    pb[n] = b2[lat * NP + p];
    pp[n] = protos[lat * NP + p];
  }
  const float act_scale = 300.0f / logf(10000.0f);
#pragma unroll
  for (int m = 0; m < 2; ++m)
#pragma unroll
    for (int r = 0; r < 4; ++r) {
      float s = 0.f;
#pragma unroll
      for (int n = 0; n < 4; ++n) {
        const float e = acc2[m][n][r] + pb[n] - pp[n];
        s += e * e;
      }
      s += __shfl_xor(s, 1);
      s += __shfl_xor(s, 2);
      s += __shfl_xor(s, 4);
      s += __shfl_xor(s, 8);
      if (l15 == 0) {
        const float a = logf((s + 1.0f) / (s + 1e-4f)) * act_scale - 100.0f;
        const int trow = wave * 32 + m * 16 + l4 * 4 + r;
        out[(size_t)(t0 + trow) * NL + lat] = a;
      }
    }
}

extern "C" void kernel_launch(void* const* d_in, const int* in_sizes, int n_in,
                              void* d_out, int out_size, void* d_ws, size_t ws_size,
                              hipStream_t stream) {
  const float* x      = (const float*)d_in[0];
  const float* W1     = (const float*)d_in[1];
  const float* b1     = (const float*)d_in[2];
  const float* gamma  = (const float*)d_in[3];
  const float* beta   = (const float*)d_in[4];
  const float* rmean  = (const float*)d_in[5];
  const float* rvar   = (const float*)d_in[6];
  const float* W2     = (const float*)d_in[7];
  const float* b2     = (const float*)d_in[8];
  const float* protos = (const float*)d_in[9];
  float* out = (float*)d_out;

  // workspace: xq 8MB | w1q 16MB | w2b 2MB | sx 32KB | sw 64KB
  char* ws = (char*)d_ws;
  signed char*    xq  = (signed char*)ws;
  signed char*    w1q = (signed char*)(ws + (size_t)8 * 1024 * 1024);
  unsigned short* w2b = (unsigned short*)(ws + (size_t)24 * 1024 * 1024);
  float*          sx  = (float*)(ws + (size_t)26 * 1024 * 1024);
  float*          sw  = (float*)(ws + (size_t)26 * 1024 * 1024 + 64 * 1024);

  quant_rows_i8<<<NTOK / 4, 256, 0, stream>>>(x, xq, sx, NTOK);
  quant_rows_i8<<<NL * NH / 4, 256, 0, stream>>>(W1, w1q, sw, NL * NH);
  {
    const int n8w2 = NL * NP * NH / 8;
    cvt_f32_bf16<<<(n8w2 + 255) / 256, 256, 0, stream>>>(W2, w2b, n8w2);
  }

  dim3 grid(NTOK / 128, NL);
  proto_fused<<<grid, 256, 0, stream>>>(xq, w1q, w2b, sx, sw, b1, gamma, beta,
                                        rmean, rvar, b2, protos, out);
}